// Round 10
// baseline (750.950 us; speedup 1.0000x reference)
//
#include <hip/hip_runtime.h>

typedef float  f32x4  __attribute__((ext_vector_type(4)));
typedef float  f32x16 __attribute__((ext_vector_type(16)));
typedef short  short8 __attribute__((ext_vector_type(8)));
typedef unsigned int uint4v __attribute__((ext_vector_type(4)));

#define LOG2E 1.4426950408889634f
#define NPIX 4096
#define CCH  512
#define DQK  64

__device__ __forceinline__ ushort f2b(float f) {
  union { float f; unsigned u; } v; v.f = f;
  unsigned r = v.u + 0x7fffu + ((v.u >> 16) & 1u);
  return (ushort)(r >> 16);
}

__device__ __forceinline__ unsigned cvt_pk_bf16(float lo, float hi) {
  unsigned r;
  asm("v_cvt_pk_bf16_f32 %0, %1, %2" : "=v"(r) : "v"(lo), "v"(hi));
  return r;
}

// in-place half-swap: a' = {a[0:32), b[0:32)}, b' = {a[32:64), b[32:64)}
__device__ __forceinline__ void plane_swap(unsigned &a, unsigned &b) {
  asm volatile("v_permlane32_swap_b32 %0, %1" : "+v"(a), "+v"(b));
}

// async 16B global -> LDS (dest = wave-uniform base + lane*16)
__device__ __forceinline__ void gload16(const ushort* g, ushort* l) {
  __builtin_amdgcn_global_load_lds((const __attribute__((address_space(1))) void*)g,
                                   (__attribute__((address_space(3))) void*)l, 16, 0, 0);
}

// x: [B][C][N] f32  ->  Xt: [B][N][C] bf16  (tiled transpose via LDS)
__global__ __launch_bounds__(256) void k_cast_x(const float* __restrict__ x,
                                                ushort* __restrict__ Xt) {
  __shared__ float tile[32][33];
  const int b = blockIdx.z;
  const int n0 = blockIdx.x * 32, c0 = blockIdx.y * 32;
  const int t = threadIdx.x;
  {
    int cc = t >> 3, nn = (t & 7) * 4;
    const float4 v = *(const float4*)&x[((size_t)b * CCH + c0 + cc) * NPIX + n0 + nn];
    tile[cc][nn] = v.x; tile[cc][nn + 1] = v.y; tile[cc][nn + 2] = v.z; tile[cc][nn + 3] = v.w;
  }
  __syncthreads();
  {
    int nr = t >> 3, c4 = (t & 7) * 4;
    ushort4 o;
    o.x = f2b(tile[c4 + 0][nr]); o.y = f2b(tile[c4 + 1][nr]);
    o.z = f2b(tile[c4 + 2][nr]); o.w = f2b(tile[c4 + 3][nr]);
    *(ushort4*)&Xt[((size_t)b * NPIX + n0 + nr) * CCH + c0 + c4] = o;
  }
}

// pack wq(64x512), wk(64x512), wv(512x512) -> Wb[640][512] bf16
__global__ __launch_bounds__(256) void k_cast_w(const float* __restrict__ wq,
                                                const float* __restrict__ wk,
                                                const float* __restrict__ wv,
                                                ushort* __restrict__ Wb) {
  int i = blockIdx.x * 256 + threadIdx.x;
  int idx = i * 4;
  int j = idx >> 9, c = idx & 511;
  const float* src = (j < 64) ? &wq[(size_t)j * 512]
                   : (j < 128) ? &wk[(size_t)(j - 64) * 512]
                               : &wv[(size_t)(j - 128) * 512];
  float4 v = *(const float4*)&src[c];
  ushort4 o; o.x = f2b(v.x); o.y = f2b(v.y); o.z = f2b(v.z); o.w = f2b(v.w);
  *(ushort4*)&Wb[idx] = o;
}

// QKV projection GEMM: out[j,n] = sum_c Wb[j,c]*Xt[n,c] + bias[j]
// Q: [B][N][64] (pre-scaled by LOG2E), K: [B][N][64], V: [B][C][N]  (all bf16)
__global__ __launch_bounds__(256) void k_proj(const ushort* __restrict__ Xt,
                                              const ushort* __restrict__ Wb,
                                              const float* __restrict__ bq,
                                              const float* __restrict__ bk,
                                              const float* __restrict__ bv,
                                              ushort* __restrict__ Q,
                                              ushort* __restrict__ K,
                                              ushort* __restrict__ V) {
  __shared__ ushort Wl[64][72];
  __shared__ ushort Xl[64][72];
  const int b = blockIdx.z;
  const int n0 = blockIdx.x * 64;
  const int j0 = blockIdx.y * 64;
  const int t = threadIdx.x;
  const int w = t >> 6, l = t & 63;
  const int lr = l & 15, lq = l >> 4;
  const int wj = (w >> 1) * 32, wn = (w & 1) * 32;

  f32x4 acc[2][2];
#pragma unroll
  for (int a = 0; a < 2; ++a)
#pragma unroll
    for (int c = 0; c < 2; ++c) acc[a][c] = f32x4{0.f, 0.f, 0.f, 0.f};

  const int srow = t >> 2, sch = t & 3;
  for (int k0 = 0; k0 < 512; k0 += 64) {
    *(uint4*)&Wl[srow][sch * 8]       = *(const uint4*)&Wb[(size_t)(j0 + srow) * 512 + k0 + sch * 8];
    *(uint4*)&Wl[srow][(sch + 4) * 8] = *(const uint4*)&Wb[(size_t)(j0 + srow) * 512 + k0 + (sch + 4) * 8];
    *(uint4*)&Xl[srow][sch * 8]       = *(const uint4*)&Xt[((size_t)b * NPIX + n0 + srow) * 512 + k0 + sch * 8];
    *(uint4*)&Xl[srow][(sch + 4) * 8] = *(const uint4*)&Xt[((size_t)b * NPIX + n0 + srow) * 512 + k0 + (sch + 4) * 8];
    __syncthreads();
#pragma unroll
    for (int kt = 0; kt < 2; ++kt) {
      short8 af[2], bf[2];
#pragma unroll
      for (int jt = 0; jt < 2; ++jt)
        af[jt] = *(const short8*)&Wl[wj + jt * 16 + lr][kt * 32 + lq * 8];
#pragma unroll
      for (int nt = 0; nt < 2; ++nt)
        bf[nt] = *(const short8*)&Xl[wn + nt * 16 + lr][kt * 32 + lq * 8];
#pragma unroll
      for (int jt = 0; jt < 2; ++jt)
#pragma unroll
        for (int nt = 0; nt < 2; ++nt)
          acc[jt][nt] = __builtin_amdgcn_mfma_f32_16x16x32_bf16(af[jt], bf[nt], acc[jt][nt], 0, 0, 0);
    }
    __syncthreads();
  }

#pragma unroll
  for (int jt = 0; jt < 2; ++jt) {
    const int jb = j0 + wj + jt * 16;
#pragma unroll
    for (int nt = 0; nt < 2; ++nt) {
      const int n = n0 + wn + nt * 16 + lr;
      const size_t nrow = (size_t)b * NPIX + n;
      if (jb < 64) {
        // Q pre-scaled by LOG2E so attention uses exp2 directly
        ushort4 o;
        o.x = f2b(LOG2E * (acc[jt][nt][0] + bq[jb + lq * 4 + 0]));
        o.y = f2b(LOG2E * (acc[jt][nt][1] + bq[jb + lq * 4 + 1]));
        o.z = f2b(LOG2E * (acc[jt][nt][2] + bq[jb + lq * 4 + 2]));
        o.w = f2b(LOG2E * (acc[jt][nt][3] + bq[jb + lq * 4 + 3]));
        *(ushort4*)&Q[nrow * DQK + jb + lq * 4] = o;
      } else if (jb < 128) {
        ushort4 o;
        o.x = f2b(acc[jt][nt][0] + bk[jb - 64 + lq * 4 + 0]);
        o.y = f2b(acc[jt][nt][1] + bk[jb - 64 + lq * 4 + 1]);
        o.z = f2b(acc[jt][nt][2] + bk[jb - 64 + lq * 4 + 2]);
        o.w = f2b(acc[jt][nt][3] + bk[jb - 64 + lq * 4 + 3]);
        *(ushort4*)&K[nrow * DQK + jb - 64 + lq * 4] = o;
      } else {
#pragma unroll
        for (int r = 0; r < 4; ++r) {
          int cch = jb - 128 + lq * 4 + r;
          V[((size_t)b * CCH + cch) * NPIX + n] = f2b(acc[jt][nt][r] + bv[cch]);
        }
      }
    }
  }
}

// flash attention v10: R8 math with 256-thr blocks for 2 blocks/CU co-residency.
// 4 waves = 4 q-strips(64q); each wave covers the block's full 128c.
// block = 256q x 128c; grid = 16qb x 4cb x 8b = 512 blocks = 2/CU (m114 overlap).
// 3 LDS bufs x 24KB (K 64x64 | V 128x64) = 72KB; depth-2 prefetch; counted
// s_waitcnt vmcnt(6). P = exp2(S), Q pre-scaled by LOG2E. All state in named regs.
__global__ __launch_bounds__(256, 2) void k_attn(const ushort* __restrict__ Qb,
                                                 const ushort* __restrict__ Kb,
                                                 const ushort* __restrict__ Vb,
                                                 const float* __restrict__ x,
                                                 const float* __restrict__ gamma,
                                                 float* __restrict__ out) {
  __shared__ ushort Sl[3][12288];            // per buf: K 64x64 (4096 us) | V 128x64 (8192 us)
  const int id = blockIdx.x;
  const int b  = id & 7;                     // XCD via %8 round-robin
  const int s_ = id >> 3;                    // 0..63 within XCD
  const int cb = s_ >> 4;                    // 4 c-slices of 128
  const int qb = s_ & 15;                    // 16 q-blocks (consecutive per cb)
  const int t = threadIdx.x;
  const int w = t >> 6, l = t & 63;
  const int lq = l & 31, h = l >> 5;
  const int qw = qb * 256 + w * 64;          // wave's 64-query strip
  const int swz = (lq & 7) << 3;

  // Q fragments (B-operand): lane holds Q[qw+qt*32+lq][ks*16 + h*8 ..]
  short8 qf0[4], qf1[4];
#pragma unroll
  for (int ks = 0; ks < 4; ++ks) {
    qf0[ks] = *(const short8*)&Qb[((size_t)b * NPIX + qw + lq) * DQK + ks * 16 + h * 8];
    qf1[ks] = *(const short8*)&Qb[((size_t)b * NPIX + qw + 32 + lq) * DQK + ks * 16 + h * 8];
  }

  f32x16 acc0[4] = {};                       // q rows 0..31 of strip
  f32x16 acc1[4] = {};                       // q rows 32..63
  float L0 = 0.f, L1 = 0.f;

  const size_t kg = (size_t)b * NPIX * DQK;
  const size_t vg = ((size_t)b * CCH + cb * 128) * NPIX;

  auto stage = [&](int buf, int key0) {
#pragma unroll
    for (int i = 0; i < 2; ++i) {             // K: 512 chunks of 16B, 2/thread
      const int chunk = i * 256 + t;
      const int row = chunk >> 3, cc = chunk & 7;
      gload16(Kb + kg + (size_t)(key0 + row) * DQK + ((cc ^ (row & 7)) << 3),
              &Sl[buf][i * 2048 + w * 512]);
    }
#pragma unroll
    for (int i = 0; i < 4; ++i) {             // V: 1024 chunks of 16B, 4/thread
      const int chunk = i * 256 + t;
      const int row = chunk >> 3, cc = chunk & 7;
      gload16(Vb + vg + (size_t)row * NPIX + key0 + ((cc ^ (row & 7)) << 3),
              &Sl[buf][4096 + i * 2048 + w * 512]);
    }
  };

  stage(0, 0);
  stage(1, 64);
  asm volatile("s_waitcnt vmcnt(6)" ::: "memory");   // buf0 complete
  __builtin_amdgcn_sched_barrier(0);
  __builtin_amdgcn_s_barrier();
  __builtin_amdgcn_sched_barrier(0);

  const int NT = NPIX / 64;
  int buf = 0;
  for (int tt = 0; tt < NT; ++tt) {
    if (tt + 2 < NT) stage((tt + 2) % 3, (tt + 2) * 64);
    const ushort* KL = &Sl[buf][0];
    const ushort* VL = &Sl[buf][4096];

#pragma unroll
    for (int rd = 0; rd < 2; ++rd) {
      short8 kf[4];
#pragma unroll
      for (int ks = 0; ks < 4; ++ks)
        kf[ks] = *(const short8*)&KL[(size_t)(rd * 32 + lq) * 64 + ((ks * 16 + h * 8) ^ swz)];

      // S^T = K * Q^T (rows = keys, cols = queries; lane's query = lq)
      f32x16 s0 = {}, s1 = {};
      __builtin_amdgcn_s_setprio(1);
#pragma unroll
      for (int ks = 0; ks < 4; ++ks) {
        s0 = __builtin_amdgcn_mfma_f32_32x32x16_bf16(kf[ks], qf0[ks], s0, 0, 0, 0);
        s1 = __builtin_amdgcn_mfma_f32_32x32x16_bf16(kf[ks], qf1[ks], s1, 0, 0, 0);
      }
      __builtin_amdgcn_s_setprio(0);

      // softmax qt0: P = exp2(S') in-place, rowsum, pack to bf16 B-fragments
      float sum0 = 0.f;
#pragma unroll
      for (int r = 0; r < 16; ++r) { s0[r] = __builtin_amdgcn_exp2f(s0[r]); sum0 += s0[r]; }
      L0 += sum0;
      unsigned pk0[8];
#pragma unroll
      for (int j = 0; j < 8; ++j) pk0[j] = cvt_pk_bf16(s0[2 * j], s0[2 * j + 1]);
      plane_swap(pk0[0], pk0[2]); plane_swap(pk0[1], pk0[3]);
      plane_swap(pk0[4], pk0[6]); plane_swap(pk0[5], pk0[7]);
      union { uint4v u; short8 s8; } B00, B10;
      B00.u[0] = pk0[0]; B00.u[1] = pk0[1]; B00.u[2] = pk0[2]; B00.u[3] = pk0[3];
      B10.u[0] = pk0[4]; B10.u[1] = pk0[5]; B10.u[2] = pk0[6]; B10.u[3] = pk0[7];

      // softmax qt1
      float sum1 = 0.f;
#pragma unroll
      for (int r = 0; r < 16; ++r) { s1[r] = __builtin_amdgcn_exp2f(s1[r]); sum1 += s1[r]; }
      L1 += sum1;
      unsigned pk1[8];
#pragma unroll
      for (int j = 0; j < 8; ++j) pk1[j] = cvt_pk_bf16(s1[2 * j], s1[2 * j + 1]);
      plane_swap(pk1[0], pk1[2]); plane_swap(pk1[1], pk1[3]);
      plane_swap(pk1[4], pk1[6]); plane_swap(pk1[5], pk1[7]);
      union { uint4v u; short8 s8; } B01, B11;
      B01.u[0] = pk1[0]; B01.u[1] = pk1[1]; B01.u[2] = pk1[2]; B01.u[3] = pk1[3];
      B11.u[0] = pk1[4]; B11.u[1] = pk1[5]; B11.u[2] = pk1[6]; B11.u[3] = pk1[7];

      // PV: each V fragment pair feeds both q-tiles (2x MFMA per LDS byte)
      __builtin_amdgcn_s_setprio(1);
#pragma unroll
      for (int ct = 0; ct < 4; ++ct) {
        const size_t vrow = (size_t)(ct * 32 + lq) * 64;
        short8 v0 = *(const short8*)&VL[vrow + ((rd * 32 + 0 + h * 8) ^ swz)];
        short8 v1 = *(const short8*)&VL[vrow + ((rd * 32 + 16 + h * 8) ^ swz)];
        acc0[ct] = __builtin_amdgcn_mfma_f32_32x32x16_bf16(v0, B00.s8, acc0[ct], 0, 0, 0);
        acc0[ct] = __builtin_amdgcn_mfma_f32_32x32x16_bf16(v1, B10.s8, acc0[ct], 0, 0, 0);
        acc1[ct] = __builtin_amdgcn_mfma_f32_32x32x16_bf16(v0, B01.s8, acc1[ct], 0, 0, 0);
        acc1[ct] = __builtin_amdgcn_mfma_f32_32x32x16_bf16(v1, B11.s8, acc1[ct], 0, 0, 0);
      }
      __builtin_amdgcn_s_setprio(0);
    }

    if (tt + 2 < NT) { asm volatile("s_waitcnt vmcnt(6)" ::: "memory"); }
    else             { asm volatile("s_waitcnt vmcnt(0)" ::: "memory"); }
    __builtin_amdgcn_sched_barrier(0);
    __builtin_amdgcn_s_barrier();
    __builtin_amdgcn_sched_barrier(0);
    buf = (buf == 2) ? 0 : buf + 1;
  }

  // epilogue: out[b][c][n] = gamma * O/L + x  (32 contiguous f32 per half-wave)
  L0 += __shfl_xor(L0, 32);
  L1 += __shfl_xor(L1, 32);
  const float g = gamma[0];
  const float gi0 = g / L0, gi1 = g / L1;
#pragma unroll
  for (int ct = 0; ct < 4; ++ct)
#pragma unroll
    for (int r = 0; r < 16; ++r) {
      const int c = cb * 128 + ct * 32 + (r & 3) + 8 * (r >> 2) + 4 * h;
      const size_t base = ((size_t)b * CCH + c) * NPIX + qw + lq;
      out[base] = gi0 * acc0[ct][r] + x[base];
      out[base + 32] = gi1 * acc1[ct][r] + x[base + 32];
    }
}

extern "C" void kernel_launch(void* const* d_in, const int* in_sizes, int n_in,
                              void* d_out, int out_size, void* d_ws, size_t ws_size,
                              hipStream_t stream) {
  const float* x     = (const float*)d_in[0];
  const float* wq    = (const float*)d_in[1];
  const float* bq    = (const float*)d_in[2];
  const float* wk    = (const float*)d_in[3];
  const float* bk    = (const float*)d_in[4];
  const float* wv    = (const float*)d_in[5];
  const float* bv    = (const float*)d_in[6];
  const float* gamma = (const float*)d_in[7];
  float* out = (float*)d_out;

  // Xt (32MB bf16) lives in d_out (64MB) — dead before k_attn writes the output.
  ushort* Xt = (ushort*)d_out;
  ushort* Wb = (ushort*)d_ws;                          // 640*512
  ushort* Qb = Wb + (size_t)640 * 512;                 // 8*4096*64
  ushort* Kb = Qb + (size_t)8 * NPIX * DQK;            // 8*4096*64
  ushort* Vb = Kb + (size_t)8 * NPIX * DQK;            // 8*512*4096
  // total ws: ~42.6 MB

  k_cast_x<<<dim3(NPIX / 32, CCH / 32, 8), 256, 0, stream>>>(x, Xt);
  k_cast_w<<<(640 * 512 / 4) / 256, 256, 0, stream>>>(wq, wk, wv, Wb);
  k_proj<<<dim3(NPIX / 64, 640 / 64, 8), 256, 0, stream>>>(Xt, Wb, bq, bk, bv, Qb, Kb, Vb);
  k_attn<<<dim3(512), 256, 0, stream>>>(Qb, Kb, Vb, x, gamma, out);
}

// Round 11
// 350.753 us; speedup vs baseline: 2.1410x; 2.1410x over previous
//
#include <hip/hip_runtime.h>

typedef float  f32x4  __attribute__((ext_vector_type(4)));
typedef float  f32x16 __attribute__((ext_vector_type(16)));
typedef short  short8 __attribute__((ext_vector_type(8)));
typedef unsigned int uint4v __attribute__((ext_vector_type(4)));

#define LOG2E 1.4426950408889634f
#define NPIX 4096
#define CCH  512
#define DQK  64

__device__ __forceinline__ ushort f2b(float f) {
  union { float f; unsigned u; } v; v.f = f;
  unsigned r = v.u + 0x7fffu + ((v.u >> 16) & 1u);
  return (ushort)(r >> 16);
}

__device__ __forceinline__ unsigned cvt_pk_bf16(float lo, float hi) {
  unsigned r;
  asm("v_cvt_pk_bf16_f32 %0, %1, %2" : "=v"(r) : "v"(lo), "v"(hi));
  return r;
}

// in-place half-swap: a' = {a[0:32), b[0:32)}, b' = {a[32:64), b[32:64)}
__device__ __forceinline__ void plane_swap(unsigned &a, unsigned &b) {
  asm volatile("v_permlane32_swap_b32 %0, %1" : "+v"(a), "+v"(b));
}

// async 16B global -> LDS (dest = wave-uniform base + lane*16)
__device__ __forceinline__ void gload16(const ushort* g, ushort* l) {
  __builtin_amdgcn_global_load_lds((const __attribute__((address_space(1))) void*)g,
                                   (__attribute__((address_space(3))) void*)l, 16, 0, 0);
}

// x: [B][C][N] f32  ->  Xt: [B][N][C] bf16  (tiled transpose via LDS)
__global__ __launch_bounds__(256) void k_cast_x(const float* __restrict__ x,
                                                ushort* __restrict__ Xt) {
  __shared__ float tile[32][33];
  const int b = blockIdx.z;
  const int n0 = blockIdx.x * 32, c0 = blockIdx.y * 32;
  const int t = threadIdx.x;
  {
    int cc = t >> 3, nn = (t & 7) * 4;
    const float4 v = *(const float4*)&x[((size_t)b * CCH + c0 + cc) * NPIX + n0 + nn];
    tile[cc][nn] = v.x; tile[cc][nn + 1] = v.y; tile[cc][nn + 2] = v.z; tile[cc][nn + 3] = v.w;
  }
  __syncthreads();
  {
    int nr = t >> 3, c4 = (t & 7) * 4;
    ushort4 o;
    o.x = f2b(tile[c4 + 0][nr]); o.y = f2b(tile[c4 + 1][nr]);
    o.z = f2b(tile[c4 + 2][nr]); o.w = f2b(tile[c4 + 3][nr]);
    *(ushort4*)&Xt[((size_t)b * NPIX + n0 + nr) * CCH + c0 + c4] = o;
  }
}

// pack wq(64x512), wk(64x512), wv(512x512) -> Wb[640][512] bf16
__global__ __launch_bounds__(256) void k_cast_w(const float* __restrict__ wq,
                                                const float* __restrict__ wk,
                                                const float* __restrict__ wv,
                                                ushort* __restrict__ Wb) {
  int i = blockIdx.x * 256 + threadIdx.x;
  int idx = i * 4;
  int j = idx >> 9, c = idx & 511;
  const float* src = (j < 64) ? &wq[(size_t)j * 512]
                   : (j < 128) ? &wk[(size_t)(j - 64) * 512]
                               : &wv[(size_t)(j - 128) * 512];
  float4 v = *(const float4*)&src[c];
  ushort4 o; o.x = f2b(v.x); o.y = f2b(v.y); o.z = f2b(v.z); o.w = f2b(v.w);
  *(ushort4*)&Wb[idx] = o;
}

// QKV projection GEMM: out[j,n] = sum_c Wb[j,c]*Xt[n,c] + bias[j]
// Q: [B][N][64] (pre-scaled by LOG2E), K: [B][N][64], V: [B][C][N]  (all bf16)
__global__ __launch_bounds__(256) void k_proj(const ushort* __restrict__ Xt,
                                              const ushort* __restrict__ Wb,
                                              const float* __restrict__ bq,
                                              const float* __restrict__ bk,
                                              const float* __restrict__ bv,
                                              ushort* __restrict__ Q,
                                              ushort* __restrict__ K,
                                              ushort* __restrict__ V) {
  __shared__ ushort Wl[64][72];
  __shared__ ushort Xl[64][72];
  const int b = blockIdx.z;
  const int n0 = blockIdx.x * 64;
  const int j0 = blockIdx.y * 64;
  const int t = threadIdx.x;
  const int w = t >> 6, l = t & 63;
  const int lr = l & 15, lq = l >> 4;
  const int wj = (w >> 1) * 32, wn = (w & 1) * 32;

  f32x4 acc[2][2];
#pragma unroll
  for (int a = 0; a < 2; ++a)
#pragma unroll
    for (int c = 0; c < 2; ++c) acc[a][c] = f32x4{0.f, 0.f, 0.f, 0.f};

  const int srow = t >> 2, sch = t & 3;
  for (int k0 = 0; k0 < 512; k0 += 64) {
    *(uint4*)&Wl[srow][sch * 8]       = *(const uint4*)&Wb[(size_t)(j0 + srow) * 512 + k0 + sch * 8];
    *(uint4*)&Wl[srow][(sch + 4) * 8] = *(const uint4*)&Wb[(size_t)(j0 + srow) * 512 + k0 + (sch + 4) * 8];
    *(uint4*)&Xl[srow][sch * 8]       = *(const uint4*)&Xt[((size_t)b * NPIX + n0 + srow) * 512 + k0 + sch * 8];
    *(uint4*)&Xl[srow][(sch + 4) * 8] = *(const uint4*)&Xt[((size_t)b * NPIX + n0 + srow) * 512 + k0 + (sch + 4) * 8];
    __syncthreads();
#pragma unroll
    for (int kt = 0; kt < 2; ++kt) {
      short8 af[2], bf[2];
#pragma unroll
      for (int jt = 0; jt < 2; ++jt)
        af[jt] = *(const short8*)&Wl[wj + jt * 16 + lr][kt * 32 + lq * 8];
#pragma unroll
      for (int nt = 0; nt < 2; ++nt)
        bf[nt] = *(const short8*)&Xl[wn + nt * 16 + lr][kt * 32 + lq * 8];
#pragma unroll
      for (int jt = 0; jt < 2; ++jt)
#pragma unroll
        for (int nt = 0; nt < 2; ++nt)
          acc[jt][nt] = __builtin_amdgcn_mfma_f32_16x16x32_bf16(af[jt], bf[nt], acc[jt][nt], 0, 0, 0);
    }
    __syncthreads();
  }

#pragma unroll
  for (int jt = 0; jt < 2; ++jt) {
    const int jb = j0 + wj + jt * 16;
#pragma unroll
    for (int nt = 0; nt < 2; ++nt) {
      const int n = n0 + wn + nt * 16 + lr;
      const size_t nrow = (size_t)b * NPIX + n;
      if (jb < 64) {
        // Q pre-scaled by LOG2E so attention uses exp2 directly
        ushort4 o;
        o.x = f2b(LOG2E * (acc[jt][nt][0] + bq[jb + lq * 4 + 0]));
        o.y = f2b(LOG2E * (acc[jt][nt][1] + bq[jb + lq * 4 + 1]));
        o.z = f2b(LOG2E * (acc[jt][nt][2] + bq[jb + lq * 4 + 2]));
        o.w = f2b(LOG2E * (acc[jt][nt][3] + bq[jb + lq * 4 + 3]));
        *(ushort4*)&Q[nrow * DQK + jb + lq * 4] = o;
      } else if (jb < 128) {
        ushort4 o;
        o.x = f2b(acc[jt][nt][0] + bk[jb - 64 + lq * 4 + 0]);
        o.y = f2b(acc[jt][nt][1] + bk[jb - 64 + lq * 4 + 1]);
        o.z = f2b(acc[jt][nt][2] + bk[jb - 64 + lq * 4 + 2]);
        o.w = f2b(acc[jt][nt][3] + bk[jb - 64 + lq * 4 + 3]);
        *(ushort4*)&K[nrow * DQK + jb - 64 + lq * 4] = o;
      } else {
#pragma unroll
        for (int r = 0; r < 4; ++r) {
          int cch = jb - 128 + lq * 4 + r;
          V[((size_t)b * CCH + cch) * NPIX + n] = f2b(acc[jt][nt][r] + bv[cch]);
        }
      }
    }
  }
}

// flash attention v11: R8 geometry + within-tile rd-pipelining.
// 512 thr / 8 waves = 4 q-strips(64q) x 2 c-groups(128c); block 256q x 256c;
// grid 256 = 1 block/CU. Per tile: QK(rd0) -> QK(rd1) -> softmax(rd0) ->
// PV(rd0) -> softmax(rd1) -> PV(rd1): the second QK burst hides the first
// S-result latency; PV(rd0) hides the second. Staging/vmcnt ledger identical
// to R8 (3 bufs, depth-2, counted vmcnt(5)). Tree-sum softmax.
__global__ __launch_bounds__(512, 1) void k_attn(const ushort* __restrict__ Qb,
                                                 const ushort* __restrict__ Kb,
                                                 const ushort* __restrict__ Vb,
                                                 const float* __restrict__ x,
                                                 const float* __restrict__ gamma,
                                                 float* __restrict__ out) {
  __shared__ ushort Sl[3][20480];            // per buf: K 64x64 (4096 us) | V 256x64 (16384 us)
  const int id = blockIdx.x;
  const int b  = id & 7;                     // XCD via %8 round-robin
  const int s_ = id >> 3;                    // 0..31 within XCD
  const int cb = s_ >> 4;                    // 2 c-slices of 256
  const int qb = s_ & 15;                    // 16 q-blocks (consecutive per cb)
  const int t = threadIdx.x;
  const int w = t >> 6, l = t & 63;
  const int lq = l & 31, h = l >> 5;
  const int qw = qb * 256 + (w >> 1) * 64;   // wave's 64-query strip
  const int cloc = (w & 1) * 128;            // wave's local c-base within 256
  const int swz = (lq & 7) << 3;

  union PB { uint4v u; short8 s8; };

  // Q fragments (B-operand): lane holds Q[qw+qt*32+lq][ks*16 + h*8 ..]
  short8 qf0[4], qf1[4];
#pragma unroll
  for (int ks = 0; ks < 4; ++ks) {
    qf0[ks] = *(const short8*)&Qb[((size_t)b * NPIX + qw + lq) * DQK + ks * 16 + h * 8];
    qf1[ks] = *(const short8*)&Qb[((size_t)b * NPIX + qw + 32 + lq) * DQK + ks * 16 + h * 8];
  }

  f32x16 acc0[4] = {};                       // q rows 0..31 of strip
  f32x16 acc1[4] = {};                       // q rows 32..63
  float L0 = 0.f, L1 = 0.f;

  const size_t kg = (size_t)b * NPIX * DQK;
  const size_t vg = ((size_t)b * CCH + cb * 256) * NPIX;

  auto stage = [&](int buf, int key0) {
    {                                         // K: 512 chunks of 16B, 1/thread
      const int row = t >> 3, cc = t & 7;
      gload16(Kb + kg + (size_t)(key0 + row) * DQK + ((cc ^ (row & 7)) << 3),
              &Sl[buf][w * 512]);
    }
#pragma unroll
    for (int i = 0; i < 4; ++i) {             // V: 2048 chunks of 16B, 4/thread
      const int chunk = i * 512 + t;
      const int row = chunk >> 3, cc = chunk & 7;
      gload16(Vb + vg + (size_t)row * NPIX + key0 + ((cc ^ (row & 7)) << 3),
              &Sl[buf][4096 + i * 4096 + w * 512]);
    }
  };

  stage(0, 0);
  stage(1, 64);
  asm volatile("s_waitcnt vmcnt(5)" ::: "memory");   // buf0 complete
  __builtin_amdgcn_sched_barrier(0);
  __builtin_amdgcn_s_barrier();
  __builtin_amdgcn_sched_barrier(0);

  const int NT = NPIX / 64;
  int buf = 0;
  for (int tt = 0; tt < NT; ++tt) {
    if (tt + 2 < NT) stage((tt + 2) % 3, (tt + 2) * 64);
    const ushort* KL = &Sl[buf][0];
    const ushort* VL = &Sl[buf][4096];

    // ---- QK rd0 -> s0,s1
    f32x16 s0 = {}, s1 = {};
    {
      short8 kA = *(const short8*)&KL[(size_t)(0 + lq) * 64 + (( 0 + h * 8) ^ swz)];
      short8 kB = *(const short8*)&KL[(size_t)(0 + lq) * 64 + ((16 + h * 8) ^ swz)];
      short8 kC = *(const short8*)&KL[(size_t)(0 + lq) * 64 + ((32 + h * 8) ^ swz)];
      short8 kD = *(const short8*)&KL[(size_t)(0 + lq) * 64 + ((48 + h * 8) ^ swz)];
      __builtin_amdgcn_s_setprio(1);
      s0 = __builtin_amdgcn_mfma_f32_32x32x16_bf16(kA, qf0[0], s0, 0, 0, 0);
      s1 = __builtin_amdgcn_mfma_f32_32x32x16_bf16(kA, qf1[0], s1, 0, 0, 0);
      s0 = __builtin_amdgcn_mfma_f32_32x32x16_bf16(kB, qf0[1], s0, 0, 0, 0);
      s1 = __builtin_amdgcn_mfma_f32_32x32x16_bf16(kB, qf1[1], s1, 0, 0, 0);
      s0 = __builtin_amdgcn_mfma_f32_32x32x16_bf16(kC, qf0[2], s0, 0, 0, 0);
      s1 = __builtin_amdgcn_mfma_f32_32x32x16_bf16(kC, qf1[2], s1, 0, 0, 0);
      s0 = __builtin_amdgcn_mfma_f32_32x32x16_bf16(kD, qf0[3], s0, 0, 0, 0);
      s1 = __builtin_amdgcn_mfma_f32_32x32x16_bf16(kD, qf1[3], s1, 0, 0, 0);
      __builtin_amdgcn_s_setprio(0);
    }

    // ---- QK rd1 -> t0,t1 (issues while s0,s1 results land)
    f32x16 t0 = {}, t1 = {};
    {
      short8 kA = *(const short8*)&KL[(size_t)(32 + lq) * 64 + (( 0 + h * 8) ^ swz)];
      short8 kB = *(const short8*)&KL[(size_t)(32 + lq) * 64 + ((16 + h * 8) ^ swz)];
      short8 kC = *(const short8*)&KL[(size_t)(32 + lq) * 64 + ((32 + h * 8) ^ swz)];
      short8 kD = *(const short8*)&KL[(size_t)(32 + lq) * 64 + ((48 + h * 8) ^ swz)];
      __builtin_amdgcn_s_setprio(1);
      t0 = __builtin_amdgcn_mfma_f32_32x32x16_bf16(kA, qf0[0], t0, 0, 0, 0);
      t1 = __builtin_amdgcn_mfma_f32_32x32x16_bf16(kA, qf1[0], t1, 0, 0, 0);
      t0 = __builtin_amdgcn_mfma_f32_32x32x16_bf16(kB, qf0[1], t0, 0, 0, 0);
      t1 = __builtin_amdgcn_mfma_f32_32x32x16_bf16(kB, qf1[1], t1, 0, 0, 0);
      t0 = __builtin_amdgcn_mfma_f32_32x32x16_bf16(kC, qf0[2], t0, 0, 0, 0);
      t1 = __builtin_amdgcn_mfma_f32_32x32x16_bf16(kC, qf1[2], t1, 0, 0, 0);
      t0 = __builtin_amdgcn_mfma_f32_32x32x16_bf16(kD, qf0[3], t0, 0, 0, 0);
      t1 = __builtin_amdgcn_mfma_f32_32x32x16_bf16(kD, qf1[3], t1, 0, 0, 0);
      __builtin_amdgcn_s_setprio(0);
    }

    PB B00, B10, B01, B11;

    // ---- softmax rd0 (tree-sum; P = exp2(S'), Q pre-scaled by log2e)
    {
#pragma unroll
      for (int r = 0; r < 16; ++r) s0[r] = __builtin_amdgcn_exp2f(s0[r]);
      float a0 = (s0[0] + s0[1]) + (s0[2] + s0[3]);
      float a1 = (s0[4] + s0[5]) + (s0[6] + s0[7]);
      float a2 = (s0[8] + s0[9]) + (s0[10] + s0[11]);
      float a3 = (s0[12] + s0[13]) + (s0[14] + s0[15]);
      L0 += (a0 + a1) + (a2 + a3);
      unsigned p0 = cvt_pk_bf16(s0[0],  s0[1]),  p1 = cvt_pk_bf16(s0[2],  s0[3]);
      unsigned p2 = cvt_pk_bf16(s0[4],  s0[5]),  p3 = cvt_pk_bf16(s0[6],  s0[7]);
      unsigned p4 = cvt_pk_bf16(s0[8],  s0[9]),  p5 = cvt_pk_bf16(s0[10], s0[11]);
      unsigned p6 = cvt_pk_bf16(s0[12], s0[13]), p7 = cvt_pk_bf16(s0[14], s0[15]);
      plane_swap(p0, p2); plane_swap(p1, p3); plane_swap(p4, p6); plane_swap(p5, p7);
      B00.u[0] = p0; B00.u[1] = p1; B00.u[2] = p2; B00.u[3] = p3;
      B10.u[0] = p4; B10.u[1] = p5; B10.u[2] = p6; B10.u[3] = p7;
#pragma unroll
      for (int r = 0; r < 16; ++r) s1[r] = __builtin_amdgcn_exp2f(s1[r]);
      float b0 = (s1[0] + s1[1]) + (s1[2] + s1[3]);
      float b1 = (s1[4] + s1[5]) + (s1[6] + s1[7]);
      float b2 = (s1[8] + s1[9]) + (s1[10] + s1[11]);
      float b3 = (s1[12] + s1[13]) + (s1[14] + s1[15]);
      L1 += (b0 + b1) + (b2 + b3);
      unsigned q0_ = cvt_pk_bf16(s1[0],  s1[1]),  q1_ = cvt_pk_bf16(s1[2],  s1[3]);
      unsigned q2_ = cvt_pk_bf16(s1[4],  s1[5]),  q3_ = cvt_pk_bf16(s1[6],  s1[7]);
      unsigned q4_ = cvt_pk_bf16(s1[8],  s1[9]),  q5_ = cvt_pk_bf16(s1[10], s1[11]);
      unsigned q6_ = cvt_pk_bf16(s1[12], s1[13]), q7_ = cvt_pk_bf16(s1[14], s1[15]);
      plane_swap(q0_, q2_); plane_swap(q1_, q3_); plane_swap(q4_, q6_); plane_swap(q5_, q7_);
      B01.u[0] = q0_; B01.u[1] = q1_; B01.u[2] = q2_; B01.u[3] = q3_;
      B11.u[0] = q4_; B11.u[1] = q5_; B11.u[2] = q6_; B11.u[3] = q7_;
    }

    // ---- PV rd0 (t0,t1 results land under these MFMAs)
    __builtin_amdgcn_s_setprio(1);
#pragma unroll
    for (int ct = 0; ct < 4; ++ct) {
      const size_t vrow = (size_t)(cloc + ct * 32 + lq) * 64;
      short8 v0 = *(const short8*)&VL[vrow + (( 0 + h * 8) ^ swz)];
      short8 v1 = *(const short8*)&VL[vrow + ((16 + h * 8) ^ swz)];
      acc0[ct] = __builtin_amdgcn_mfma_f32_32x32x16_bf16(v0, B00.s8, acc0[ct], 0, 0, 0);
      acc0[ct] = __builtin_amdgcn_mfma_f32_32x32x16_bf16(v1, B10.s8, acc0[ct], 0, 0, 0);
      acc1[ct] = __builtin_amdgcn_mfma_f32_32x32x16_bf16(v0, B01.s8, acc1[ct], 0, 0, 0);
      acc1[ct] = __builtin_amdgcn_mfma_f32_32x32x16_bf16(v1, B11.s8, acc1[ct], 0, 0, 0);
    }
    __builtin_amdgcn_s_setprio(0);

    // ---- softmax rd1
    {
#pragma unroll
      for (int r = 0; r < 16; ++r) t0[r] = __builtin_amdgcn_exp2f(t0[r]);
      float a0 = (t0[0] + t0[1]) + (t0[2] + t0[3]);
      float a1 = (t0[4] + t0[5]) + (t0[6] + t0[7]);
      float a2 = (t0[8] + t0[9]) + (t0[10] + t0[11]);
      float a3 = (t0[12] + t0[13]) + (t0[14] + t0[15]);
      L0 += (a0 + a1) + (a2 + a3);
      unsigned p0 = cvt_pk_bf16(t0[0],  t0[1]),  p1 = cvt_pk_bf16(t0[2],  t0[3]);
      unsigned p2 = cvt_pk_bf16(t0[4],  t0[5]),  p3 = cvt_pk_bf16(t0[6],  t0[7]);
      unsigned p4 = cvt_pk_bf16(t0[8],  t0[9]),  p5 = cvt_pk_bf16(t0[10], t0[11]);
      unsigned p6 = cvt_pk_bf16(t0[12], t0[13]), p7 = cvt_pk_bf16(t0[14], t0[15]);
      plane_swap(p0, p2); plane_swap(p1, p3); plane_swap(p4, p6); plane_swap(p5, p7);
      B00.u[0] = p0; B00.u[1] = p1; B00.u[2] = p2; B00.u[3] = p3;
      B10.u[0] = p4; B10.u[1] = p5; B10.u[2] = p6; B10.u[3] = p7;
#pragma unroll
      for (int r = 0; r < 16; ++r) t1[r] = __builtin_amdgcn_exp2f(t1[r]);
      float b0 = (t1[0] + t1[1]) + (t1[2] + t1[3]);
      float b1 = (t1[4] + t1[5]) + (t1[6] + t1[7]);
      float b2 = (t1[8] + t1[9]) + (t1[10] + t1[11]);
      float b3 = (t1[12] + t1[13]) + (t1[14] + t1[15]);
      L1 += (b0 + b1) + (b2 + b3);
      unsigned q0_ = cvt_pk_bf16(t1[0],  t1[1]),  q1_ = cvt_pk_bf16(t1[2],  t1[3]);
      unsigned q2_ = cvt_pk_bf16(t1[4],  t1[5]),  q3_ = cvt_pk_bf16(t1[6],  t1[7]);
      unsigned q4_ = cvt_pk_bf16(t1[8],  t1[9]),  q5_ = cvt_pk_bf16(t1[10], t1[11]);
      unsigned q6_ = cvt_pk_bf16(t1[12], t1[13]), q7_ = cvt_pk_bf16(t1[14], t1[15]);
      plane_swap(q0_, q2_); plane_swap(q1_, q3_); plane_swap(q4_, q6_); plane_swap(q5_, q7_);
      B01.u[0] = q0_; B01.u[1] = q1_; B01.u[2] = q2_; B01.u[3] = q3_;
      B11.u[0] = q4_; B11.u[1] = q5_; B11.u[2] = q6_; B11.u[3] = q7_;
    }

    // ---- PV rd1
    __builtin_amdgcn_s_setprio(1);
#pragma unroll
    for (int ct = 0; ct < 4; ++ct) {
      const size_t vrow = (size_t)(cloc + ct * 32 + lq) * 64;
      short8 v0 = *(const short8*)&VL[vrow + ((32 + h * 8) ^ swz)];
      short8 v1 = *(const short8*)&VL[vrow + ((48 + h * 8) ^ swz)];
      acc0[ct] = __builtin_amdgcn_mfma_f32_32x32x16_bf16(v0, B00.s8, acc0[ct], 0, 0, 0);
      acc0[ct] = __builtin_amdgcn_mfma_f32_32x32x16_bf16(v1, B10.s8, acc0[ct], 0, 0, 0);
      acc1[ct] = __builtin_amdgcn_mfma_f32_32x32x16_bf16(v0, B01.s8, acc1[ct], 0, 0, 0);
      acc1[ct] = __builtin_amdgcn_mfma_f32_32x32x16_bf16(v1, B11.s8, acc1[ct], 0, 0, 0);
    }
    __builtin_amdgcn_s_setprio(0);

    if (tt + 2 < NT) { asm volatile("s_waitcnt vmcnt(5)" ::: "memory"); }
    else             { asm volatile("s_waitcnt vmcnt(0)" ::: "memory"); }
    __builtin_amdgcn_sched_barrier(0);
    __builtin_amdgcn_s_barrier();
    __builtin_amdgcn_sched_barrier(0);
    buf = (buf == 2) ? 0 : buf + 1;
  }

  // epilogue: out[b][c][n] = gamma * O/L + x  (32 contiguous f32 per half-wave)
  L0 += __shfl_xor(L0, 32);
  L1 += __shfl_xor(L1, 32);
  const float g = gamma[0];
  const float gi0 = g / L0, gi1 = g / L1;
#pragma unroll
  for (int ct = 0; ct < 4; ++ct)
#pragma unroll
    for (int r = 0; r < 16; ++r) {
      const int c = cb * 256 + cloc + ct * 32 + (r & 3) + 8 * (r >> 2) + 4 * h;
      const size_t base = ((size_t)b * CCH + c) * NPIX + qw + lq;
      out[base] = gi0 * acc0[ct][r] + x[base];
      out[base + 32] = gi1 * acc1[ct][r] + x[base + 32];
    }
}

extern "C" void kernel_launch(void* const* d_in, const int* in_sizes, int n_in,
                              void* d_out, int out_size, void* d_ws, size_t ws_size,
                              hipStream_t stream) {
  const float* x     = (const float*)d_in[0];
  const float* wq    = (const float*)d_in[1];
  const float* bq    = (const float*)d_in[2];
  const float* wk    = (const float*)d_in[3];
  const float* bk    = (const float*)d_in[4];
  const float* wv    = (const float*)d_in[5];
  const float* bv    = (const float*)d_in[6];
  const float* gamma = (const float*)d_in[7];
  float* out = (float*)d_out;

  // Xt (32MB bf16) lives in d_out (64MB) — dead before k_attn writes the output.
  ushort* Xt = (ushort*)d_out;
  ushort* Wb = (ushort*)d_ws;                          // 640*512
  ushort* Qb = Wb + (size_t)640 * 512;                 // 8*4096*64
  ushort* Kb = Qb + (size_t)8 * NPIX * DQK;            // 8*4096*64
  ushort* Vb = Kb + (size_t)8 * NPIX * DQK;            // 8*512*4096
  // total ws: ~42.6 MB

  k_cast_x<<<dim3(NPIX / 32, CCH / 32, 8), 256, 0, stream>>>(x, Xt);
  k_cast_w<<<(640 * 512 / 4) / 256, 256, 0, stream>>>(wq, wk, wv, Wb);
  k_proj<<<dim3(NPIX / 64, 640 / 64, 8), 256, 0, stream>>>(Xt, Wb, bq, bk, bv, Qb, Kb, Vb);
  k_attn<<<dim3(256), 512, 0, stream>>>(Qb, Kb, Vb, x, gamma, out);
}

// Round 12
// 340.558 us; speedup vs baseline: 2.2051x; 1.0299x over previous
//
#include <hip/hip_runtime.h>

typedef float  f32x4  __attribute__((ext_vector_type(4)));
typedef float  f32x16 __attribute__((ext_vector_type(16)));
typedef short  short8 __attribute__((ext_vector_type(8)));
typedef unsigned int uint4v __attribute__((ext_vector_type(4)));

#define LOG2E 1.4426950408889634f
#define NPIX 4096
#define CCH  512
#define DQK  64

__device__ __forceinline__ ushort f2b(float f) {
  union { float f; unsigned u; } v; v.f = f;
  unsigned r = v.u + 0x7fffu + ((v.u >> 16) & 1u);
  return (ushort)(r >> 16);
}

__device__ __forceinline__ unsigned cvt_pk_bf16(float lo, float hi) {
  unsigned r;
  asm("v_cvt_pk_bf16_f32 %0, %1, %2" : "=v"(r) : "v"(lo), "v"(hi));
  return r;
}

// in-place half-swap: a' = {a[0:32), b[0:32)}, b' = {a[32:64), b[32:64)}
__device__ __forceinline__ void plane_swap(unsigned &a, unsigned &b) {
  asm volatile("v_permlane32_swap_b32 %0, %1" : "+v"(a), "+v"(b));
}

// x: [B][C][N] f32  ->  Xt: [B][N][C] bf16  (tiled transpose via LDS)
__global__ __launch_bounds__(256) void k_cast_x(const float* __restrict__ x,
                                                ushort* __restrict__ Xt) {
  __shared__ float tile[32][33];
  const int b = blockIdx.z;
  const int n0 = blockIdx.x * 32, c0 = blockIdx.y * 32;
  const int t = threadIdx.x;
  {
    int cc = t >> 3, nn = (t & 7) * 4;
    const float4 v = *(const float4*)&x[((size_t)b * CCH + c0 + cc) * NPIX + n0 + nn];
    tile[cc][nn] = v.x; tile[cc][nn + 1] = v.y; tile[cc][nn + 2] = v.z; tile[cc][nn + 3] = v.w;
  }
  __syncthreads();
  {
    int nr = t >> 3, c4 = (t & 7) * 4;
    ushort4 o;
    o.x = f2b(tile[c4 + 0][nr]); o.y = f2b(tile[c4 + 1][nr]);
    o.z = f2b(tile[c4 + 2][nr]); o.w = f2b(tile[c4 + 3][nr]);
    *(ushort4*)&Xt[((size_t)b * NPIX + n0 + nr) * CCH + c0 + c4] = o;
  }
}

// pack wq(64x512), wk(64x512), wv(512x512) -> Wb[640][512] bf16
__global__ __launch_bounds__(256) void k_cast_w(const float* __restrict__ wq,
                                                const float* __restrict__ wk,
                                                const float* __restrict__ wv,
                                                ushort* __restrict__ Wb) {
  int i = blockIdx.x * 256 + threadIdx.x;
  int idx = i * 4;
  int j = idx >> 9, c = idx & 511;
  const float* src = (j < 64) ? &wq[(size_t)j * 512]
                   : (j < 128) ? &wk[(size_t)(j - 64) * 512]
                               : &wv[(size_t)(j - 128) * 512];
  float4 v = *(const float4*)&src[c];
  ushort4 o; o.x = f2b(v.x); o.y = f2b(v.y); o.z = f2b(v.z); o.w = f2b(v.w);
  *(ushort4*)&Wb[idx] = o;
}

// QKV projection GEMM: out[j,n] = sum_c Wb[j,c]*Xt[n,c] + bias[j]
// Q: [B][N][64] row-major (pre-scaled by LOG2E).
// K: fragment-order Kf[b][n32][ks:4][lane:64][e:8]  (lane holds K[n32*32+(l&31)][ks*16+(l>>5)*8+e])
// V: fragment-order Vf[b][n32][c32:16][kt:2][lane:64][e:8] (lane holds V[c32*32+(l&31)][n32*32+kt*16+(l>>5)*8+e])
__global__ __launch_bounds__(256) void k_proj(const ushort* __restrict__ Xt,
                                              const ushort* __restrict__ Wb,
                                              const float* __restrict__ bq,
                                              const float* __restrict__ bk,
                                              const float* __restrict__ bv,
                                              ushort* __restrict__ Q,
                                              ushort* __restrict__ Kf,
                                              ushort* __restrict__ Vf) {
  __shared__ ushort Wl[64][72];
  __shared__ ushort Xl[64][72];
  const int b = blockIdx.z;
  const int n0 = blockIdx.x * 64;
  const int j0 = blockIdx.y * 64;
  const int t = threadIdx.x;
  const int w = t >> 6, l = t & 63;
  const int lr = l & 15, lq = l >> 4;
  const int wj = (w >> 1) * 32, wn = (w & 1) * 32;

  f32x4 acc[2][2];
#pragma unroll
  for (int a = 0; a < 2; ++a)
#pragma unroll
    for (int c = 0; c < 2; ++c) acc[a][c] = f32x4{0.f, 0.f, 0.f, 0.f};

  const int srow = t >> 2, sch = t & 3;
  for (int k0 = 0; k0 < 512; k0 += 64) {
    *(uint4*)&Wl[srow][sch * 8]       = *(const uint4*)&Wb[(size_t)(j0 + srow) * 512 + k0 + sch * 8];
    *(uint4*)&Wl[srow][(sch + 4) * 8] = *(const uint4*)&Wb[(size_t)(j0 + srow) * 512 + k0 + (sch + 4) * 8];
    *(uint4*)&Xl[srow][sch * 8]       = *(const uint4*)&Xt[((size_t)b * NPIX + n0 + srow) * 512 + k0 + sch * 8];
    *(uint4*)&Xl[srow][(sch + 4) * 8] = *(const uint4*)&Xt[((size_t)b * NPIX + n0 + srow) * 512 + k0 + (sch + 4) * 8];
    __syncthreads();
#pragma unroll
    for (int kt = 0; kt < 2; ++kt) {
      short8 af[2], bf[2];
#pragma unroll
      for (int jt = 0; jt < 2; ++jt)
        af[jt] = *(const short8*)&Wl[wj + jt * 16 + lr][kt * 32 + lq * 8];
#pragma unroll
      for (int nt = 0; nt < 2; ++nt)
        bf[nt] = *(const short8*)&Xl[wn + nt * 16 + lr][kt * 32 + lq * 8];
#pragma unroll
      for (int jt = 0; jt < 2; ++jt)
#pragma unroll
        for (int nt = 0; nt < 2; ++nt)
          acc[jt][nt] = __builtin_amdgcn_mfma_f32_16x16x32_bf16(af[jt], bf[nt], acc[jt][nt], 0, 0, 0);
    }
    __syncthreads();
  }

#pragma unroll
  for (int jt = 0; jt < 2; ++jt) {
    const int jb = j0 + wj + jt * 16;
#pragma unroll
    for (int nt = 0; nt < 2; ++nt) {
      const int n = n0 + wn + nt * 16 + lr;
      const size_t nrow = (size_t)b * NPIX + n;
      const int n32 = (n0 + wn) >> 5;          // n0+wn is 32-aligned; nt*16+lr < 32
      if (jb < 64) {
        // Q row-major, pre-scaled by LOG2E so attention uses exp2 directly
        ushort4 o;
        o.x = f2b(LOG2E * (acc[jt][nt][0] + bq[jb + lq * 4 + 0]));
        o.y = f2b(LOG2E * (acc[jt][nt][1] + bq[jb + lq * 4 + 1]));
        o.z = f2b(LOG2E * (acc[jt][nt][2] + bq[jb + lq * 4 + 2]));
        o.w = f2b(LOG2E * (acc[jt][nt][3] + bq[jb + lq * 4 + 3]));
        *(ushort4*)&Q[nrow * DQK + jb + lq * 4] = o;
      } else if (jb < 128) {
        // K fragment-order: kd = jb-64+lq*4+r, row = n
        const int kd0 = jb - 64 + lq * 4;
        const int ks = (jb - 64) >> 4;
        const int hl = lq >> 1;                // (lq*4)>>3
        const int e0 = (lq * 4) & 7;
        const int lp = (nt * 16 + lr) + 32 * hl;
        ushort4 o;
        o.x = f2b(acc[jt][nt][0] + bk[kd0 + 0]);
        o.y = f2b(acc[jt][nt][1] + bk[kd0 + 1]);
        o.z = f2b(acc[jt][nt][2] + bk[kd0 + 2]);
        o.w = f2b(acc[jt][nt][3] + bk[kd0 + 3]);
        *(ushort4*)&Kf[((size_t)(b * 128 + n32) * 4 + ks) * 512 + lp * 8 + e0] = o;
      } else {
        // V fragment-order: kt=(n>>4)&1=nt, hlv=(n>>3)&1, e=n&7
        const int kt = nt;
        const int hlv = (lr >> 3) & 1;
        const int e = lr & 7;
#pragma unroll
        for (int r = 0; r < 4; ++r) {
          const int c = jb - 128 + lq * 4 + r;
          Vf[(((size_t)(b * 128 + n32) * 16 + (c >> 5)) * 2 + kt) * 512 +
             (c & 31) * 8 + 256 * hlv + e] = f2b(acc[jt][nt][r] + bv[c]);
        }
      }
    }
  }
}

// flash attention v12: NO LDS, NO barriers. Fragment-order K/V from global
// (every load = coalesced 1KB wave-load through L2). 512 thr / 8 waves =
// 4 q-strips(64q) x 2 c-groups(128c); block 256q x 256c; grid 256 = 1/CU.
// Single-buffered fragments, T14 issue-after-last-use prefetch (K between
// softmax halves, V after PV). Compiler-managed waitcnts. R8 math unchanged.
__global__ __launch_bounds__(512, 1) void k_attn(const ushort* __restrict__ Qb,
                                                 const ushort* __restrict__ Kf,
                                                 const ushort* __restrict__ Vf,
                                                 const float* __restrict__ x,
                                                 const float* __restrict__ gamma,
                                                 float* __restrict__ out) {
  const int id = blockIdx.x;
  const int b  = id & 7;                     // XCD via %8 round-robin
  const int s_ = id >> 3;                    // 0..31 within XCD
  const int cb = s_ >> 4;                    // 2 c-slices of 256
  const int qb = s_ & 15;                    // 16 q-blocks
  const int t = threadIdx.x;
  const int w = t >> 6, l = t & 63;
  const int lq = l & 31, h = l >> 5;
  const int qw = qb * 256 + (w >> 1) * 64;   // wave's 64-query strip
  const int cloc = (w & 1) * 128;            // wave's local c-base within 256
  const int c32b = cb * 8 + (w & 1) * 4;     // wave's first c32 tile

  union PB { uint4v u; short8 s8; };

  // Q fragments (B-operand): lane holds Q[qw+qt*32+lq][ks*16 + h*8 ..]
  short8 qf0[4], qf1[4];
#pragma unroll
  for (int ks = 0; ks < 4; ++ks) {
    qf0[ks] = *(const short8*)&Qb[((size_t)b * NPIX + qw + lq) * DQK + ks * 16 + h * 8];
    qf1[ks] = *(const short8*)&Qb[((size_t)b * NPIX + qw + 32 + lq) * DQK + ks * 16 + h * 8];
  }

  f32x16 acc0[4] = {};                       // q rows 0..31 of strip
  f32x16 acc1[4] = {};                       // q rows 32..63
  float L0 = 0.f, L1 = 0.f;

  // per-lane fragment base pointers (elem units)
  const ushort* kbase = Kf + (size_t)b * 128 * 2048 + (size_t)l * 8;
  const ushort* vbase = Vf + (size_t)b * 128 * 16384 + (size_t)c32b * 1024 + (size_t)l * 8;

  short8 kf[4];                              // single-buffered K fragments
  short8 vf[8];                              // vf[ct*2+kt]

  // prologue: loads for step 0
  {
    const ushort* pk = kbase;
    kf[0] = *(const short8*)(pk);
    kf[1] = *(const short8*)(pk + 512);
    kf[2] = *(const short8*)(pk + 1024);
    kf[3] = *(const short8*)(pk + 1536);
    const ushort* pv = vbase;
#pragma unroll
    for (int i = 0; i < 8; ++i)
      vf[i] = *(const short8*)(pv + i * 512);
  }

  for (int n32 = 0; n32 < 128; ++n32) {
    const int nn = (n32 < 127) ? n32 + 1 : 127;

    // S^T = K * Q^T (rows = keys, cols = queries; lane's query = lq)
    f32x16 s0 = {}, s1 = {};
    __builtin_amdgcn_s_setprio(1);
#pragma unroll
    for (int ks = 0; ks < 4; ++ks) {
      s0 = __builtin_amdgcn_mfma_f32_32x32x16_bf16(kf[ks], qf0[ks], s0, 0, 0, 0);
      s1 = __builtin_amdgcn_mfma_f32_32x32x16_bf16(kf[ks], qf1[ks], s1, 0, 0, 0);
    }
    __builtin_amdgcn_s_setprio(0);

    // softmax qt0: P = exp2(S') in-place, rowsum, pack to bf16 B-fragments
    float sum0 = 0.f;
#pragma unroll
    for (int r = 0; r < 16; ++r) { s0[r] = __builtin_amdgcn_exp2f(s0[r]); sum0 += s0[r]; }
    L0 += sum0;
    unsigned pk0[8];
#pragma unroll
    for (int j = 0; j < 8; ++j) pk0[j] = cvt_pk_bf16(s0[2 * j], s0[2 * j + 1]);
    plane_swap(pk0[0], pk0[2]); plane_swap(pk0[1], pk0[3]);
    plane_swap(pk0[4], pk0[6]); plane_swap(pk0[5], pk0[7]);
    PB B00, B10;
    B00.u[0] = pk0[0]; B00.u[1] = pk0[1]; B00.u[2] = pk0[2]; B00.u[3] = pk0[3];
    B10.u[0] = pk0[4]; B10.u[1] = pk0[5]; B10.u[2] = pk0[6]; B10.u[3] = pk0[7];

    // prefetch K(nn) — kf dead since QK; lands under softmax1+PV
    {
      const ushort* pk = kbase + (size_t)nn * 2048;
      kf[0] = *(const short8*)(pk);
      kf[1] = *(const short8*)(pk + 512);
      kf[2] = *(const short8*)(pk + 1024);
      kf[3] = *(const short8*)(pk + 1536);
    }
    __builtin_amdgcn_sched_barrier(0);

    // softmax qt1
    float sum1 = 0.f;
#pragma unroll
    for (int r = 0; r < 16; ++r) { s1[r] = __builtin_amdgcn_exp2f(s1[r]); sum1 += s1[r]; }
    L1 += sum1;
    unsigned pk1[8];
#pragma unroll
    for (int j = 0; j < 8; ++j) pk1[j] = cvt_pk_bf16(s1[2 * j], s1[2 * j + 1]);
    plane_swap(pk1[0], pk1[2]); plane_swap(pk1[1], pk1[3]);
    plane_swap(pk1[4], pk1[6]); plane_swap(pk1[5], pk1[7]);
    PB B01, B11;
    B01.u[0] = pk1[0]; B01.u[1] = pk1[1]; B01.u[2] = pk1[2]; B01.u[3] = pk1[3];
    B11.u[0] = pk1[4]; B11.u[1] = pk1[5]; B11.u[2] = pk1[6]; B11.u[3] = pk1[7];

    // PV: each V fragment pair feeds both q-tiles
    __builtin_amdgcn_s_setprio(1);
#pragma unroll
    for (int ct = 0; ct < 4; ++ct) {
      acc0[ct] = __builtin_amdgcn_mfma_f32_32x32x16_bf16(vf[ct * 2 + 0], B00.s8, acc0[ct], 0, 0, 0);
      acc0[ct] = __builtin_amdgcn_mfma_f32_32x32x16_bf16(vf[ct * 2 + 1], B10.s8, acc0[ct], 0, 0, 0);
      acc1[ct] = __builtin_amdgcn_mfma_f32_32x32x16_bf16(vf[ct * 2 + 0], B01.s8, acc1[ct], 0, 0, 0);
      acc1[ct] = __builtin_amdgcn_mfma_f32_32x32x16_bf16(vf[ct * 2 + 1], B11.s8, acc1[ct], 0, 0, 0);
    }
    __builtin_amdgcn_s_setprio(0);

    // prefetch V(nn) — vf dead after PV; lands under next QK+softmax0
    {
      const ushort* pv = vbase + (size_t)nn * 16384;
#pragma unroll
      for (int i = 0; i < 8; ++i)
        vf[i] = *(const short8*)(pv + i * 512);
    }
    __builtin_amdgcn_sched_barrier(0);
  }

  // epilogue: out[b][c][n] = gamma * O/L + x  (32 contiguous f32 per half-wave)
  L0 += __shfl_xor(L0, 32);
  L1 += __shfl_xor(L1, 32);
  const float g = gamma[0];
  const float gi0 = g / L0, gi1 = g / L1;
#pragma unroll
  for (int ct = 0; ct < 4; ++ct)
#pragma unroll
    for (int r = 0; r < 16; ++r) {
      const int c = cb * 256 + cloc + ct * 32 + (r & 3) + 8 * (r >> 2) + 4 * h;
      const size_t base = ((size_t)b * CCH + c) * NPIX + qw + lq;
      out[base] = gi0 * acc0[ct][r] + x[base];
      out[base + 32] = gi1 * acc1[ct][r] + x[base + 32];
    }
}

extern "C" void kernel_launch(void* const* d_in, const int* in_sizes, int n_in,
                              void* d_out, int out_size, void* d_ws, size_t ws_size,
                              hipStream_t stream) {
  const float* x     = (const float*)d_in[0];
  const float* wq    = (const float*)d_in[1];
  const float* bq    = (const float*)d_in[2];
  const float* wk    = (const float*)d_in[3];
  const float* bk    = (const float*)d_in[4];
  const float* wv    = (const float*)d_in[5];
  const float* bv    = (const float*)d_in[6];
  const float* gamma = (const float*)d_in[7];
  float* out = (float*)d_out;

  // Xt (32MB bf16) lives in d_out (64MB) — dead before k_attn writes the output.
  ushort* Xt = (ushort*)d_out;
  ushort* Wb = (ushort*)d_ws;                          // 640*512
  ushort* Qb = Wb + (size_t)640 * 512;                 // 8*4096*64 row-major
  ushort* Kf = Qb + (size_t)8 * NPIX * DQK;            // 8*128*4*512  (fragment-order)
  ushort* Vf = Kf + (size_t)8 * 128 * 4 * 512;         // 8*128*16*2*512 (fragment-order)
  // total ws: ~42.8 MB

  k_cast_x<<<dim3(NPIX / 32, CCH / 32, 8), 256, 0, stream>>>(x, Xt);
  k_cast_w<<<(640 * 512 / 4) / 256, 256, 0, stream>>>(wq, wk, wv, Wb);
  k_proj<<<dim3(NPIX / 64, 640 / 64, 8), 256, 0, stream>>>(Xt, Wb, bq, bk, bv, Qb, Kf, Vf);
  k_attn<<<dim3(256), 512, 0, stream>>>(Qb, Kf, Vf, x, gamma, out);
}

// Round 13
// 336.371 us; speedup vs baseline: 2.2325x; 1.0124x over previous
//
#include <hip/hip_runtime.h>

typedef float  f32x4  __attribute__((ext_vector_type(4)));
typedef float  f32x16 __attribute__((ext_vector_type(16)));
typedef short  short8 __attribute__((ext_vector_type(8)));
typedef unsigned int uint4v __attribute__((ext_vector_type(4)));

#define LOG2E 1.4426950408889634f
#define NPIX 4096
#define CCH  512
#define DQK  64

__device__ __forceinline__ ushort f2b(float f) {
  union { float f; unsigned u; } v; v.f = f;
  unsigned r = v.u + 0x7fffu + ((v.u >> 16) & 1u);
  return (ushort)(r >> 16);
}

__device__ __forceinline__ unsigned cvt_pk_bf16(float lo, float hi) {
  unsigned r;
  asm("v_cvt_pk_bf16_f32 %0, %1, %2" : "=v"(r) : "v"(lo), "v"(hi));
  return r;
}

// in-place half-swap: a' = {a[0:32), b[0:32)}, b' = {a[32:64), b[32:64)}
__device__ __forceinline__ void plane_swap(unsigned &a, unsigned &b) {
  asm volatile("v_permlane32_swap_b32 %0, %1" : "+v"(a), "+v"(b));
}

// x: [B][C][N] f32  ->  Xt: [B][N][C] bf16  (tiled transpose via LDS)
__global__ __launch_bounds__(256) void k_cast_x(const float* __restrict__ x,
                                                ushort* __restrict__ Xt) {
  __shared__ float tile[32][33];
  const int b = blockIdx.z;
  const int n0 = blockIdx.x * 32, c0 = blockIdx.y * 32;
  const int t = threadIdx.x;
  {
    int cc = t >> 3, nn = (t & 7) * 4;
    const float4 v = *(const float4*)&x[((size_t)b * CCH + c0 + cc) * NPIX + n0 + nn];
    tile[cc][nn] = v.x; tile[cc][nn + 1] = v.y; tile[cc][nn + 2] = v.z; tile[cc][nn + 3] = v.w;
  }
  __syncthreads();
  {
    int nr = t >> 3, c4 = (t & 7) * 4;
    ushort4 o;
    o.x = f2b(tile[c4 + 0][nr]); o.y = f2b(tile[c4 + 1][nr]);
    o.z = f2b(tile[c4 + 2][nr]); o.w = f2b(tile[c4 + 3][nr]);
    *(ushort4*)&Xt[((size_t)b * NPIX + n0 + nr) * CCH + c0 + c4] = o;
  }
}

// pack wq(64x512), wk(64x512), wv(512x512) -> Wb[640][512] bf16
__global__ __launch_bounds__(256) void k_cast_w(const float* __restrict__ wq,
                                                const float* __restrict__ wk,
                                                const float* __restrict__ wv,
                                                ushort* __restrict__ Wb) {
  int i = blockIdx.x * 256 + threadIdx.x;
  int idx = i * 4;
  int j = idx >> 9, c = idx & 511;
  const float* src = (j < 64) ? &wq[(size_t)j * 512]
                   : (j < 128) ? &wk[(size_t)(j - 64) * 512]
                               : &wv[(size_t)(j - 128) * 512];
  float4 v = *(const float4*)&src[c];
  ushort4 o; o.x = f2b(v.x); o.y = f2b(v.y); o.z = f2b(v.z); o.w = f2b(v.w);
  *(ushort4*)&Wb[idx] = o;
}

// QKV projection GEMM: out[j,n] = sum_c Wb[j,c]*Xt[n,c] + bias[j]
// Q: [B][N][64] row-major (pre-scaled by LOG2E).
// K: fragment-order Kf[b][n32][ks:4][lane:64][e:8]  (lane holds K[n32*32+(l&31)][ks*16+(l>>5)*8+e])
// V: fragment-order Vf[b][n32][c32:16][kt:2][lane:64][e:8] (lane holds V[c32*32+(l&31)][n32*32+kt*16+(l>>5)*8+e])
__global__ __launch_bounds__(256) void k_proj(const ushort* __restrict__ Xt,
                                              const ushort* __restrict__ Wb,
                                              const float* __restrict__ bq,
                                              const float* __restrict__ bk,
                                              const float* __restrict__ bv,
                                              ushort* __restrict__ Q,
                                              ushort* __restrict__ Kf,
                                              ushort* __restrict__ Vf) {
  __shared__ ushort Wl[64][72];
  __shared__ ushort Xl[64][72];
  const int b = blockIdx.z;
  const int n0 = blockIdx.x * 64;
  const int j0 = blockIdx.y * 64;
  const int t = threadIdx.x;
  const int w = t >> 6, l = t & 63;
  const int lr = l & 15, lq = l >> 4;
  const int wj = (w >> 1) * 32, wn = (w & 1) * 32;

  f32x4 acc[2][2];
#pragma unroll
  for (int a = 0; a < 2; ++a)
#pragma unroll
    for (int c = 0; c < 2; ++c) acc[a][c] = f32x4{0.f, 0.f, 0.f, 0.f};

  const int srow = t >> 2, sch = t & 3;
  for (int k0 = 0; k0 < 512; k0 += 64) {
    *(uint4*)&Wl[srow][sch * 8]       = *(const uint4*)&Wb[(size_t)(j0 + srow) * 512 + k0 + sch * 8];
    *(uint4*)&Wl[srow][(sch + 4) * 8] = *(const uint4*)&Wb[(size_t)(j0 + srow) * 512 + k0 + (sch + 4) * 8];
    *(uint4*)&Xl[srow][sch * 8]       = *(const uint4*)&Xt[((size_t)b * NPIX + n0 + srow) * 512 + k0 + sch * 8];
    *(uint4*)&Xl[srow][(sch + 4) * 8] = *(const uint4*)&Xt[((size_t)b * NPIX + n0 + srow) * 512 + k0 + (sch + 4) * 8];
    __syncthreads();
#pragma unroll
    for (int kt = 0; kt < 2; ++kt) {
      short8 af[2], bf[2];
#pragma unroll
      for (int jt = 0; jt < 2; ++jt)
        af[jt] = *(const short8*)&Wl[wj + jt * 16 + lr][kt * 32 + lq * 8];
#pragma unroll
      for (int nt = 0; nt < 2; ++nt)
        bf[nt] = *(const short8*)&Xl[wn + nt * 16 + lr][kt * 32 + lq * 8];
#pragma unroll
      for (int jt = 0; jt < 2; ++jt)
#pragma unroll
        for (int nt = 0; nt < 2; ++nt)
          acc[jt][nt] = __builtin_amdgcn_mfma_f32_16x16x32_bf16(af[jt], bf[nt], acc[jt][nt], 0, 0, 0);
    }
    __syncthreads();
  }

#pragma unroll
  for (int jt = 0; jt < 2; ++jt) {
    const int jb = j0 + wj + jt * 16;
#pragma unroll
    for (int nt = 0; nt < 2; ++nt) {
      const int n = n0 + wn + nt * 16 + lr;
      const size_t nrow = (size_t)b * NPIX + n;
      const int n32 = (n0 + wn) >> 5;          // n0+wn is 32-aligned; nt*16+lr < 32
      if (jb < 64) {
        // Q row-major, pre-scaled by LOG2E so attention uses exp2 directly
        ushort4 o;
        o.x = f2b(LOG2E * (acc[jt][nt][0] + bq[jb + lq * 4 + 0]));
        o.y = f2b(LOG2E * (acc[jt][nt][1] + bq[jb + lq * 4 + 1]));
        o.z = f2b(LOG2E * (acc[jt][nt][2] + bq[jb + lq * 4 + 2]));
        o.w = f2b(LOG2E * (acc[jt][nt][3] + bq[jb + lq * 4 + 3]));
        *(ushort4*)&Q[nrow * DQK + jb + lq * 4] = o;
      } else if (jb < 128) {
        // K fragment-order: kd = jb-64+lq*4+r, row = n
        const int kd0 = jb - 64 + lq * 4;
        const int ks = (jb - 64) >> 4;
        const int hl = lq >> 1;                // (lq*4)>>3
        const int e0 = (lq * 4) & 7;
        const int lp = (nt * 16 + lr) + 32 * hl;
        ushort4 o;
        o.x = f2b(acc[jt][nt][0] + bk[kd0 + 0]);
        o.y = f2b(acc[jt][nt][1] + bk[kd0 + 1]);
        o.z = f2b(acc[jt][nt][2] + bk[kd0 + 2]);
        o.w = f2b(acc[jt][nt][3] + bk[kd0 + 3]);
        *(ushort4*)&Kf[((size_t)(b * 128 + n32) * 4 + ks) * 512 + lp * 8 + e0] = o;
      } else {
        // V fragment-order: kt=(n>>4)&1=nt, hlv=(n>>3)&1, e=n&7
        const int kt = nt;
        const int hlv = (lr >> 3) & 1;
        const int e = lr & 7;
#pragma unroll
        for (int r = 0; r < 4; ++r) {
          const int c = jb - 128 + lq * 4 + r;
          Vf[(((size_t)(b * 128 + n32) * 16 + (c >> 5)) * 2 + kt) * 512 +
             (c & 31) * 8 + 256 * hlv + e] = f2b(acc[jt][nt][r] + bv[c]);
        }
      }
    }
  }
}

// flash attention v13: NO LDS/barriers + 4 waves/SIMD.
// wave = 32q x 128c (acc 4x f32x16 = 64 regs); block = 256 thr / 4 waves =
// 4 q-strips x SAME 128c (all K/V fragment loads identical across the block
// -> L1 serves the redundancy). grid = 32qb x 4cb x 8b = 1024 = 4 blocks/CU
// = 4 waves/SIMD (launch_bounds(256,4) caps VGPR at 128). Load-use fragments,
// compiler waitcnts; 4-way TLP hides L1/L2 latency.
__global__ __launch_bounds__(256, 4) void k_attn(const ushort* __restrict__ Qb,
                                                 const ushort* __restrict__ Kf,
                                                 const ushort* __restrict__ Vf,
                                                 const float* __restrict__ x,
                                                 const float* __restrict__ gamma,
                                                 float* __restrict__ out) {
  const int id = blockIdx.x;
  const int b  = id & 7;                     // XCD via %8 round-robin
  const int s_ = id >> 3;                    // 0..127 within XCD
  const int cb = s_ >> 5;                    // 4 c-slices of 128
  const int qb = s_ & 31;                    // 32 q-blocks of 128
  const int t = threadIdx.x;
  const int w = t >> 6, l = t & 63;
  const int lq = l & 31, h = l >> 5;
  const int qw = qb * 128 + w * 32;          // wave's 32-query strip
  const int c32b = cb * 4;                   // block's first c32 tile

  union PB { uint4v u; short8 s8; };

  // Q fragments (B-operand): lane holds Q[qw+lq][ks*16 + h*8 ..]
  short8 qf[4];
#pragma unroll
  for (int ks = 0; ks < 4; ++ks)
    qf[ks] = *(const short8*)&Qb[((size_t)b * NPIX + qw + lq) * DQK + ks * 16 + h * 8];

  f32x16 acc[4] = {};
  float L = 0.f;

  // per-lane fragment base pointers (elem units)
  const ushort* kbase = Kf + (size_t)b * 128 * 2048 + (size_t)l * 8;
  const ushort* vbase = Vf + (size_t)b * 128 * 16384 + (size_t)c32b * 1024 + (size_t)l * 8;

  for (int n32 = 0; n32 < 128; ++n32) {
    // K fragments (load-use)
    const ushort* pk_ = kbase + (size_t)n32 * 2048;
    short8 kf0 = *(const short8*)(pk_);
    short8 kf1 = *(const short8*)(pk_ + 512);
    short8 kf2 = *(const short8*)(pk_ + 1024);
    short8 kf3 = *(const short8*)(pk_ + 1536);

    // S^T = K * Q^T (rows = keys, cols = queries; lane's query = lq)
    f32x16 s = {};
    __builtin_amdgcn_s_setprio(1);
    s = __builtin_amdgcn_mfma_f32_32x32x16_bf16(kf0, qf[0], s, 0, 0, 0);
    s = __builtin_amdgcn_mfma_f32_32x32x16_bf16(kf1, qf[1], s, 0, 0, 0);
    s = __builtin_amdgcn_mfma_f32_32x32x16_bf16(kf2, qf[2], s, 0, 0, 0);
    s = __builtin_amdgcn_mfma_f32_32x32x16_bf16(kf3, qf[3], s, 0, 0, 0);
    __builtin_amdgcn_s_setprio(0);

    // softmax: P = exp2(S') in-place, rowsum, pack to bf16 B-fragments
    float sum = 0.f;
#pragma unroll
    for (int r = 0; r < 16; ++r) { s[r] = __builtin_amdgcn_exp2f(s[r]); sum += s[r]; }
    L += sum;
    unsigned pk0 = cvt_pk_bf16(s[0],  s[1]),  pk1 = cvt_pk_bf16(s[2],  s[3]);
    unsigned pk2 = cvt_pk_bf16(s[4],  s[5]),  pk3 = cvt_pk_bf16(s[6],  s[7]);
    unsigned pk4 = cvt_pk_bf16(s[8],  s[9]),  pk5 = cvt_pk_bf16(s[10], s[11]);
    unsigned pk6 = cvt_pk_bf16(s[12], s[13]), pk7 = cvt_pk_bf16(s[14], s[15]);
    plane_swap(pk0, pk2); plane_swap(pk1, pk3);
    plane_swap(pk4, pk6); plane_swap(pk5, pk7);
    PB B0, B1;
    B0.u[0] = pk0; B0.u[1] = pk1; B0.u[2] = pk2; B0.u[3] = pk3;
    B1.u[0] = pk4; B1.u[1] = pk5; B1.u[2] = pk6; B1.u[3] = pk7;

    // PV: load-use V fragment pairs per c32 tile
    const ushort* pv = vbase + (size_t)n32 * 16384;
    __builtin_amdgcn_s_setprio(1);
#pragma unroll
    for (int ct = 0; ct < 4; ++ct) {
      short8 v0 = *(const short8*)(pv + ct * 1024);
      short8 v1 = *(const short8*)(pv + ct * 1024 + 512);
      acc[ct] = __builtin_amdgcn_mfma_f32_32x32x16_bf16(v0, B0.s8, acc[ct], 0, 0, 0);
      acc[ct] = __builtin_amdgcn_mfma_f32_32x32x16_bf16(v1, B1.s8, acc[ct], 0, 0, 0);
    }
    __builtin_amdgcn_s_setprio(0);
  }

  // epilogue: out[b][c][n] = gamma * O/L + x  (32 contiguous f32 per store)
  L += __shfl_xor(L, 32);
  const float gi = gamma[0] / L;
#pragma unroll
  for (int ct = 0; ct < 4; ++ct)
#pragma unroll
    for (int r = 0; r < 16; ++r) {
      const int c = cb * 128 + ct * 32 + (r & 3) + 8 * (r >> 2) + 4 * h;
      const size_t base = ((size_t)b * CCH + c) * NPIX + qw + lq;
      out[base] = gi * acc[ct][r] + x[base];
    }
}

extern "C" void kernel_launch(void* const* d_in, const int* in_sizes, int n_in,
                              void* d_out, int out_size, void* d_ws, size_t ws_size,
                              hipStream_t stream) {
  const float* x     = (const float*)d_in[0];
  const float* wq    = (const float*)d_in[1];
  const float* bq    = (const float*)d_in[2];
  const float* wk    = (const float*)d_in[3];
  const float* bk    = (const float*)d_in[4];
  const float* wv    = (const float*)d_in[5];
  const float* bv    = (const float*)d_in[6];
  const float* gamma = (const float*)d_in[7];
  float* out = (float*)d_out;

  // Xt (32MB bf16) lives in d_out (64MB) — dead before k_attn writes the output.
  ushort* Xt = (ushort*)d_out;
  ushort* Wb = (ushort*)d_ws;                          // 640*512
  ushort* Qb = Wb + (size_t)640 * 512;                 // 8*4096*64 row-major
  ushort* Kf = Qb + (size_t)8 * NPIX * DQK;            // 8*128*4*512  (fragment-order)
  ushort* Vf = Kf + (size_t)8 * 128 * 4 * 512;         // 8*128*16*2*512 (fragment-order)
  // total ws: ~42.8 MB

  k_cast_x<<<dim3(NPIX / 32, CCH / 32, 8), 256, 0, stream>>>(x, Xt);
  k_cast_w<<<(640 * 512 / 4) / 256, 256, 0, stream>>>(wq, wk, wv, Wb);
  k_proj<<<dim3(NPIX / 64, 640 / 64, 8), 256, 0, stream>>>(Xt, Wb, bq, bk, bv, Qb, Kf, Vf);
  k_attn<<<dim3(1024), 256, 0, stream>>>(Qb, Kf, Vf, x, gamma, out);
}

// Round 14
// 255.759 us; speedup vs baseline: 2.9362x; 1.3152x over previous
//
#include <hip/hip_runtime.h>

typedef float  f32x4  __attribute__((ext_vector_type(4)));
typedef float  f32x16 __attribute__((ext_vector_type(16)));
typedef short  short8 __attribute__((ext_vector_type(8)));
typedef unsigned int uint4v __attribute__((ext_vector_type(4)));

#define LOG2E 1.4426950408889634f
#define NPIX 4096
#define CCH  512
#define DQK  64

__device__ __forceinline__ ushort f2b(float f) {
  union { float f; unsigned u; } v; v.f = f;
  unsigned r = v.u + 0x7fffu + ((v.u >> 16) & 1u);
  return (ushort)(r >> 16);
}

__device__ __forceinline__ unsigned cvt_pk_bf16(float lo, float hi) {
  unsigned r;
  asm("v_cvt_pk_bf16_f32 %0, %1, %2" : "=v"(r) : "v"(lo), "v"(hi));
  return r;
}

// in-place half-swap: a' = {a[0:32), b[0:32)}, b' = {a[32:64), b[32:64)}
__device__ __forceinline__ void plane_swap(unsigned &a, unsigned &b) {
  asm volatile("v_permlane32_swap_b32 %0, %1" : "+v"(a), "+v"(b));
}

// x: [B][C][N] f32  ->  Xt: [B][N][C] bf16  (tiled transpose via LDS)
__global__ __launch_bounds__(256) void k_cast_x(const float* __restrict__ x,
                                                ushort* __restrict__ Xt) {
  __shared__ float tile[32][33];
  const int b = blockIdx.z;
  const int n0 = blockIdx.x * 32, c0 = blockIdx.y * 32;
  const int t = threadIdx.x;
  {
    int cc = t >> 3, nn = (t & 7) * 4;
    const float4 v = *(const float4*)&x[((size_t)b * CCH + c0 + cc) * NPIX + n0 + nn];
    tile[cc][nn] = v.x; tile[cc][nn + 1] = v.y; tile[cc][nn + 2] = v.z; tile[cc][nn + 3] = v.w;
  }
  __syncthreads();
  {
    int nr = t >> 3, c4 = (t & 7) * 4;
    ushort4 o;
    o.x = f2b(tile[c4 + 0][nr]); o.y = f2b(tile[c4 + 1][nr]);
    o.z = f2b(tile[c4 + 2][nr]); o.w = f2b(tile[c4 + 3][nr]);
    *(ushort4*)&Xt[((size_t)b * NPIX + n0 + nr) * CCH + c0 + c4] = o;
  }
}

// pack wq(64x512), wk(64x512), wv(512x512) -> Wb[640][512] bf16
__global__ __launch_bounds__(256) void k_cast_w(const float* __restrict__ wq,
                                                const float* __restrict__ wk,
                                                const float* __restrict__ wv,
                                                ushort* __restrict__ Wb) {
  int i = blockIdx.x * 256 + threadIdx.x;
  int idx = i * 4;
  int j = idx >> 9, c = idx & 511;
  const float* src = (j < 64) ? &wq[(size_t)j * 512]
                   : (j < 128) ? &wk[(size_t)(j - 64) * 512]
                               : &wv[(size_t)(j - 128) * 512];
  float4 v = *(const float4*)&src[c];
  ushort4 o; o.x = f2b(v.x); o.y = f2b(v.y); o.z = f2b(v.z); o.w = f2b(v.w);
  *(ushort4*)&Wb[idx] = o;
}

// QKV projection GEMM: out[j,n] = sum_c Wb[j,c]*Xt[n,c] + bias[j]
// Q: [B][N][64] row-major (pre-scaled by LOG2E).
// K: fragment-order Kf[b][n32][ks:4][lane:64][e:8]
// V: fragment-order Vf[b][n32][c32:16][kt:2][lane:64][e:8]
__global__ __launch_bounds__(256) void k_proj(const ushort* __restrict__ Xt,
                                              const ushort* __restrict__ Wb,
                                              const float* __restrict__ bq,
                                              const float* __restrict__ bk,
                                              const float* __restrict__ bv,
                                              ushort* __restrict__ Q,
                                              ushort* __restrict__ Kf,
                                              ushort* __restrict__ Vf) {
  __shared__ ushort Wl[64][72];
  __shared__ ushort Xl[64][72];
  const int b = blockIdx.z;
  const int n0 = blockIdx.x * 64;
  const int j0 = blockIdx.y * 64;
  const int t = threadIdx.x;
  const int w = t >> 6, l = t & 63;
  const int lr = l & 15, lq = l >> 4;
  const int wj = (w >> 1) * 32, wn = (w & 1) * 32;

  f32x4 acc[2][2];
#pragma unroll
  for (int a = 0; a < 2; ++a)
#pragma unroll
    for (int c = 0; c < 2; ++c) acc[a][c] = f32x4{0.f, 0.f, 0.f, 0.f};

  const int srow = t >> 2, sch = t & 3;
  for (int k0 = 0; k0 < 512; k0 += 64) {
    *(uint4*)&Wl[srow][sch * 8]       = *(const uint4*)&Wb[(size_t)(j0 + srow) * 512 + k0 + sch * 8];
    *(uint4*)&Wl[srow][(sch + 4) * 8] = *(const uint4*)&Wb[(size_t)(j0 + srow) * 512 + k0 + (sch + 4) * 8];
    *(uint4*)&Xl[srow][sch * 8]       = *(const uint4*)&Xt[((size_t)b * NPIX + n0 + srow) * 512 + k0 + sch * 8];
    *(uint4*)&Xl[srow][(sch + 4) * 8] = *(const uint4*)&Xt[((size_t)b * NPIX + n0 + srow) * 512 + k0 + (sch + 4) * 8];
    __syncthreads();
#pragma unroll
    for (int kt = 0; kt < 2; ++kt) {
      short8 af[2], bf[2];
#pragma unroll
      for (int jt = 0; jt < 2; ++jt)
        af[jt] = *(const short8*)&Wl[wj + jt * 16 + lr][kt * 32 + lq * 8];
#pragma unroll
      for (int nt = 0; nt < 2; ++nt)
        bf[nt] = *(const short8*)&Xl[wn + nt * 16 + lr][kt * 32 + lq * 8];
#pragma unroll
      for (int jt = 0; jt < 2; ++jt)
#pragma unroll
        for (int nt = 0; nt < 2; ++nt)
          acc[jt][nt] = __builtin_amdgcn_mfma_f32_16x16x32_bf16(af[jt], bf[nt], acc[jt][nt], 0, 0, 0);
    }
    __syncthreads();
  }

#pragma unroll
  for (int jt = 0; jt < 2; ++jt) {
    const int jb = j0 + wj + jt * 16;
#pragma unroll
    for (int nt = 0; nt < 2; ++nt) {
      const int n = n0 + wn + nt * 16 + lr;
      const size_t nrow = (size_t)b * NPIX + n;
      const int n32 = (n0 + wn) >> 5;
      if (jb < 64) {
        ushort4 o;
        o.x = f2b(LOG2E * (acc[jt][nt][0] + bq[jb + lq * 4 + 0]));
        o.y = f2b(LOG2E * (acc[jt][nt][1] + bq[jb + lq * 4 + 1]));
        o.z = f2b(LOG2E * (acc[jt][nt][2] + bq[jb + lq * 4 + 2]));
        o.w = f2b(LOG2E * (acc[jt][nt][3] + bq[jb + lq * 4 + 3]));
        *(ushort4*)&Q[nrow * DQK + jb + lq * 4] = o;
      } else if (jb < 128) {
        const int kd0 = jb - 64 + lq * 4;
        const int ks = (jb - 64) >> 4;
        const int hl = lq >> 1;
        const int e0 = (lq * 4) & 7;
        const int lp = (nt * 16 + lr) + 32 * hl;
        ushort4 o;
        o.x = f2b(acc[jt][nt][0] + bk[kd0 + 0]);
        o.y = f2b(acc[jt][nt][1] + bk[kd0 + 1]);
        o.z = f2b(acc[jt][nt][2] + bk[kd0 + 2]);
        o.w = f2b(acc[jt][nt][3] + bk[kd0 + 3]);
        *(ushort4*)&Kf[((size_t)(b * 128 + n32) * 4 + ks) * 512 + lp * 8 + e0] = o;
      } else {
        const int kt = nt;
        const int hlv = (lr >> 3) & 1;
        const int e = lr & 7;
#pragma unroll
        for (int r = 0; r < 4; ++r) {
          const int c = jb - 128 + lq * 4 + r;
          Vf[(((size_t)(b * 128 + n32) * 16 + (c >> 5)) * 2 + kt) * 512 +
             (c & 31) * 8 + 256 * hlv + e] = f2b(acc[jt][nt][r] + bv[c]);
        }
      }
    }
  }
}

// flash attention v14: cross-wave P-sharing. Block = 512 thr / 8 waves =
// 64q x 512c. Per 128-key tile: wave w PRODUCES S-subtile (kg=w>>1, q32=w&1)
// -> softmax -> P B-fragments to LDS (dbuf); 1 barrier; then each wave
// CONSUMES all 8 k16-slots of P for its 64c slice (32 PV MFMA). QK and
// softmax computed ONCE per (q,key). L = separable partial, reduced at end.
// grid = 64qb x 8b = 512 = 2 blocks/CU = 4 waves/SIMD (launch_bounds(512,4)).
__global__ __launch_bounds__(512, 4) void k_attn(const ushort* __restrict__ Qb,
                                                 const ushort* __restrict__ Kf,
                                                 const ushort* __restrict__ Vf,
                                                 const float* __restrict__ x,
                                                 const float* __restrict__ gamma,
                                                 float* __restrict__ out) {
  __shared__ unsigned Plds[2][8][2][2][64][2];  // [buf][k16][q32][j2][lane][pair] = 32KB
  __shared__ float Lred[2][4][32];              // [q32][kg][q] partial L sums
  const int id = blockIdx.x;
  const int b  = id & 7;                        // XCD via %8 round-robin
  const int qb = id >> 3;                       // 0..63 q-strips of 64
  const int t = threadIdx.x;
  const int w = t >> 6, l = t & 63;
  const int lq = l & 31, h = l >> 5;
  const int kg = w >> 1;                        // producer key-group 0..3
  const int q32p = w & 1;                       // producer q-subtile
  const int qw = qb * 64;

  union PB { uint4v u; short8 s8; };

  const ushort* qptr  = Qb + ((size_t)b * NPIX + qw + q32p * 32 + lq) * DQK + h * 8;
  const ushort* kbase = Kf + (size_t)b * 128 * 2048 + (size_t)l * 8;
  const ushort* vbase = Vf + (size_t)b * 128 * 16384 + (size_t)(2 * w) * 1024 + (size_t)l * 8;

  f32x16 acc[2][2] = {};                        // [q32][ct] for c = w*64 + ct*32
  float Lp = 0.f;

  for (int tile = 0; tile < 32; ++tile) {
    const int buf = tile & 1;

    // ---- producer: QK + softmax for keys [tile*128 + kg*32, +32), cols q32p
    {
      const ushort* pk_ = kbase + (size_t)(tile * 4 + kg) * 2048;
      short8 kf0 = *(const short8*)(pk_);
      short8 kf1 = *(const short8*)(pk_ + 512);
      short8 kf2 = *(const short8*)(pk_ + 1024);
      short8 kf3 = *(const short8*)(pk_ + 1536);
      short8 q0 = *(const short8*)(qptr);
      short8 q1 = *(const short8*)(qptr + 16);
      short8 q2 = *(const short8*)(qptr + 32);
      short8 q3 = *(const short8*)(qptr + 48);
      f32x16 s = {};
      __builtin_amdgcn_s_setprio(1);
      s = __builtin_amdgcn_mfma_f32_32x32x16_bf16(kf0, q0, s, 0, 0, 0);
      s = __builtin_amdgcn_mfma_f32_32x32x16_bf16(kf1, q1, s, 0, 0, 0);
      s = __builtin_amdgcn_mfma_f32_32x32x16_bf16(kf2, q2, s, 0, 0, 0);
      s = __builtin_amdgcn_mfma_f32_32x32x16_bf16(kf3, q3, s, 0, 0, 0);
      __builtin_amdgcn_s_setprio(0);

      float sum = 0.f;
#pragma unroll
      for (int r = 0; r < 16; ++r) { s[r] = __builtin_amdgcn_exp2f(s[r]); sum += s[r]; }
      Lp += sum;
      unsigned pk0 = cvt_pk_bf16(s[0],  s[1]),  pk1 = cvt_pk_bf16(s[2],  s[3]);
      unsigned pk2 = cvt_pk_bf16(s[4],  s[5]),  pk3 = cvt_pk_bf16(s[6],  s[7]);
      unsigned pk4 = cvt_pk_bf16(s[8],  s[9]),  pk5 = cvt_pk_bf16(s[10], s[11]);
      unsigned pk6 = cvt_pk_bf16(s[12], s[13]), pk7 = cvt_pk_bf16(s[14], s[15]);
      plane_swap(pk0, pk2); plane_swap(pk1, pk3);
      plane_swap(pk4, pk6); plane_swap(pk5, pk7);
      // B-frag for k16 = kg*2 (keys 0-15 of group): uints (pk0..pk3); k16+1: (pk4..pk7)
      *(uint2*)&Plds[buf][kg * 2 + 0][q32p][0][l][0] = uint2{pk0, pk1};
      *(uint2*)&Plds[buf][kg * 2 + 0][q32p][1][l][0] = uint2{pk2, pk3};
      *(uint2*)&Plds[buf][kg * 2 + 1][q32p][0][l][0] = uint2{pk4, pk5};
      *(uint2*)&Plds[buf][kg * 2 + 1][q32p][1][l][0] = uint2{pk6, pk7};
    }
    __syncthreads();

    // ---- consumer: PV over all 8 k16-slots for this wave's 64c slice
#pragma unroll
    for (int k8 = 0; k8 < 8; ++k8) {
      const ushort* pv = vbase + (size_t)(tile * 4 + (k8 >> 1)) * 16384 + (size_t)(k8 & 1) * 512;
      short8 v0 = *(const short8*)(pv);             // c32 = 2w
      short8 v1 = *(const short8*)(pv + 1024);      // c32 = 2w+1
      uint2 a0 = *(const uint2*)&Plds[buf][k8][0][0][l][0];
      uint2 a1 = *(const uint2*)&Plds[buf][k8][0][1][l][0];
      uint2 b0 = *(const uint2*)&Plds[buf][k8][1][0][l][0];
      uint2 b1 = *(const uint2*)&Plds[buf][k8][1][1][l][0];
      PB B0, B1;
      B0.u[0] = a0.x; B0.u[1] = a0.y; B0.u[2] = a1.x; B0.u[3] = a1.y;
      B1.u[0] = b0.x; B1.u[1] = b0.y; B1.u[2] = b1.x; B1.u[3] = b1.y;
      __builtin_amdgcn_s_setprio(1);
      acc[0][0] = __builtin_amdgcn_mfma_f32_32x32x16_bf16(v0, B0.s8, acc[0][0], 0, 0, 0);
      acc[0][1] = __builtin_amdgcn_mfma_f32_32x32x16_bf16(v1, B0.s8, acc[0][1], 0, 0, 0);
      acc[1][0] = __builtin_amdgcn_mfma_f32_32x32x16_bf16(v0, B1.s8, acc[1][0], 0, 0, 0);
      acc[1][1] = __builtin_amdgcn_mfma_f32_32x32x16_bf16(v1, B1.s8, acc[1][1], 0, 0, 0);
      __builtin_amdgcn_s_setprio(0);
    }
    // no trailing barrier: next tile writes the OTHER P buffer; the next
    // tile's barrier fences reuse (writer of buf t&1 at t+2 is after sync(t+1)).
  }

  // ---- L reduction across the 4 key-groups, then epilogue
  Lp += __shfl_xor(Lp, 32);
  Lred[q32p][kg][lq] = Lp;                      // both halves write same value
  __syncthreads();
  float Lt0 = (Lred[0][0][lq] + Lred[0][1][lq]) + (Lred[0][2][lq] + Lred[0][3][lq]);
  float Lt1 = (Lred[1][0][lq] + Lred[1][1][lq]) + (Lred[1][2][lq] + Lred[1][3][lq]);
  const float g = gamma[0];
  const float gi0 = g / Lt0, gi1 = g / Lt1;
#pragma unroll
  for (int ct = 0; ct < 2; ++ct)
#pragma unroll
    for (int r = 0; r < 16; ++r) {
      const int c = w * 64 + ct * 32 + (r & 3) + 8 * (r >> 2) + 4 * h;
      const size_t base = ((size_t)b * CCH + c) * NPIX + qw + lq;
      out[base]      = gi0 * acc[0][ct][r] + x[base];
      out[base + 32] = gi1 * acc[1][ct][r] + x[base + 32];
    }
}

extern "C" void kernel_launch(void* const* d_in, const int* in_sizes, int n_in,
                              void* d_out, int out_size, void* d_ws, size_t ws_size,
                              hipStream_t stream) {
  const float* x     = (const float*)d_in[0];
  const float* wq    = (const float*)d_in[1];
  const float* bq    = (const float*)d_in[2];
  const float* wk    = (const float*)d_in[3];
  const float* bk    = (const float*)d_in[4];
  const float* wv    = (const float*)d_in[5];
  const float* bv    = (const float*)d_in[6];
  const float* gamma = (const float*)d_in[7];
  float* out = (float*)d_out;

  // Xt (32MB bf16) lives in d_out (64MB) — dead before k_attn writes the output.
  ushort* Xt = (ushort*)d_out;
  ushort* Wb = (ushort*)d_ws;                          // 640*512
  ushort* Qb = Wb + (size_t)640 * 512;                 // 8*4096*64 row-major
  ushort* Kf = Qb + (size_t)8 * NPIX * DQK;            // 8*128*4*512  (fragment-order)
  ushort* Vf = Kf + (size_t)8 * 128 * 4 * 512;         // 8*128*16*2*512 (fragment-order)
  // total ws: ~42.8 MB

  k_cast_x<<<dim3(NPIX / 32, CCH / 32, 8), 256, 0, stream>>>(x, Xt);
  k_cast_w<<<(640 * 512 / 4) / 256, 256, 0, stream>>>(wq, wk, wv, Wb);
  k_proj<<<dim3(NPIX / 64, 640 / 64, 8), 256, 0, stream>>>(Xt, Wb, bq, bk, bv, Qb, Kf, Vf);
  k_attn<<<dim3(512), 512, 0, stream>>>(Qb, Kf, Vf, x, gamma, out);
}